// Round 2
// 1495.515 us; speedup vs baseline: 1.2442x; 1.2442x over previous
//
#include <hip/hip_runtime.h>
#include <type_traits>

#define DEVINL __device__ __forceinline__

typedef __fp16 f16;
typedef __fp16 f16x2 __attribute__((ext_vector_type(2)));
typedef __fp16 f16x8 __attribute__((ext_vector_type(8)));

constexpr int Hh = 8;    // hidden size
constexpr int G3 = 24;   // 3*H gate rows
constexpr int TT = 512;  // timesteps

// Activation scales folded into weights/biases at register-load time:
//   sigmoid(v) = rcp(1 + exp2(-log2e * v))
//   tanh(v)    = (1 - e2) * rcp(1 + e2),  e2 = exp2(-2*log2e * v)
constexpr float SNEG  = -1.44269504088896340736f;  // -log2(e)
constexpr float SNEG2 = -2.88539008177792681472f;  // -2*log2(e)

DEVINL float dot2(f16x2 a, f16x2 b, float c) {
#if __has_builtin(__builtin_amdgcn_fdot2)
    return __builtin_amdgcn_fdot2(a, b, c, false);   // v_dot2_f32_f16: 2 MAC/instr
#else
    return fmaf((float)a[1], (float)b[1], fmaf((float)a[0], (float)b[0], c));
#endif
}

template <typename InT, int IN_DIM>
DEVINL void load_x(f16x2* d, const InT* p) {
    if constexpr (std::is_same<InT, float>::value) {
        const float4* p4 = (const float4*)p;
#pragma unroll
        for (int q = 0; q < IN_DIM / 4; ++q) {
            float4 v = p4[q];
            d[2 * q]     = __builtin_amdgcn_cvt_pkrtz(v.x, v.y);
            d[2 * q + 1] = __builtin_amdgcn_cvt_pkrtz(v.z, v.w);
        }
    } else {
        const f16x8* p8 = (const f16x8*)p;
#pragma unroll
        for (int c = 0; c < IN_DIM / 8; ++c) {
            f16x8 v = p8[c];
            d[4 * c + 0] = __builtin_shufflevector(v, v, 0, 1);
            d[4 * c + 1] = __builtin_shufflevector(v, v, 2, 3);
            d[4 * c + 2] = __builtin_shufflevector(v, v, 4, 5);
            d[4 * c + 3] = __builtin_shufflevector(v, v, 6, 7);
        }
    }
}

// One (sequence, direction) unit per 8 lanes. Lane i owns gate rows {i, 8+i,
// 16+i}. Input projection in f16 v_dot2 (2 MAC/instr); recurrent projection in
// fp32 FMA (h-chain precision). h all-gather: 1 ds_write_b32 + 2 ds_read_b128
// per step (wave-synchronous, conflict-free) instead of 8 ds_swizzles.
// Prefetch depth 2 with manual ping-pong (no register copies).
template <typename InT, int IN_DIM, bool LAST>
__global__ __launch_bounds__(64, 2) void gru_scan(
    const InT* __restrict__ x,           // (n, T, IN_DIM)
    const float* __restrict__ Wih,       // (2, 24, IN_DIM)
    const float* __restrict__ Whh,       // (2, 24, 8)
    const float* __restrict__ bih,       // (2, 24)
    const float* __restrict__ bhh,       // (2, 24)
    f16* __restrict__ out,               // (n, T, 16): fwd->[0:8], bwd->[8:16]
    float* __restrict__ last,            // (n, 16) only when LAST
    int n)
{
    const int tid   = threadIdx.x;
    const int lane8 = tid & 7;
    const int unit  = blockIdx.x * 8 + (tid >> 3);
    const int dir   = unit >= n ? 1 : 0;       // blocks dir-uniform (n % 8 == 0)
    const int seq   = unit - dir * n;

    const int g0 = lane8, g1 = 8 + lane8, g2 = 16 + lane8;

    __shared__ __align__(16) float hsh[64];    // 8 units x 8 h-values
    const int hbase = (tid >> 3) * 8;

    // ---- weights into registers, activation scale pre-folded ----
    const float* Wd = Wih + (size_t)dir * G3 * IN_DIM;
    f16x2 wi0[IN_DIM / 2], wi1[IN_DIM / 2], wi2[IN_DIM / 2];
#pragma unroll
    for (int q = 0; q < IN_DIM / 2; ++q) {
        wi0[q] = __builtin_amdgcn_cvt_pkrtz(Wd[g0 * IN_DIM + 2 * q] * SNEG,
                                            Wd[g0 * IN_DIM + 2 * q + 1] * SNEG);
        wi1[q] = __builtin_amdgcn_cvt_pkrtz(Wd[g1 * IN_DIM + 2 * q] * SNEG,
                                            Wd[g1 * IN_DIM + 2 * q + 1] * SNEG);
        wi2[q] = __builtin_amdgcn_cvt_pkrtz(Wd[g2 * IN_DIM + 2 * q] * SNEG2,
                                            Wd[g2 * IN_DIM + 2 * q + 1] * SNEG2);
    }
    const float* Hd = Whh + (size_t)dir * G3 * Hh;
    float wh0[Hh], wh1[Hh], wh2[Hh];
#pragma unroll
    for (int k = 0; k < Hh; ++k) {
        wh0[k] = Hd[g0 * Hh + k] * SNEG;
        wh1[k] = Hd[g1 * Hh + k] * SNEG;
        wh2[k] = Hd[g2 * Hh + k] * SNEG2;
    }
    const float br  = (bih[dir * G3 + g0] + bhh[dir * G3 + g0]) * SNEG;
    const float bz  = (bih[dir * G3 + g1] + bhh[dir * G3 + g1]) * SNEG;
    const float bxn = bih[dir * G3 + g2] * SNEG2;
    const float bhn = bhh[dir * G3 + g2] * SNEG2;

    float h[Hh];
#pragma unroll
    for (int k = 0; k < Hh; ++k) h[k] = 0.f;
    float hown = 0.f;                          // this lane's own h element

    const int t0 = dir ? (TT - 1) : 0;
    const int xstep = dir ? -IN_DIM : IN_DIM;
    int xoff = (seq * TT + t0) * IN_DIM;       // 32-bit element offsets
    int ooff = (seq * TT + t0) * 16 + dir * 8 + lane8;
    const int ostep = dir ? -16 : 16;

    // layer-3 backward: only out_b[:, T-1] is consumed = its FIRST step
    const int steps = (LAST && dir) ? 1 : TT;

    f16x2 xa[IN_DIM / 2], xb[IN_DIM / 2];
    load_x<InT, IN_DIM>(xa, x + xoff); xoff += xstep;
    if (steps > 1) { load_x<InT, IN_DIM>(xb, x + xoff); xoff += xstep; }

#define GRU_STEP(XV, PF)                                                      \
    {                                                                         \
        float sr = br, sz = bz, xn = bxn;                                     \
        _Pragma("unroll")                                                     \
        for (int q = 0; q < IN_DIM / 2; ++q) {                                \
            sr = dot2(wi0[q], XV[q], sr);                                     \
            sz = dot2(wi1[q], XV[q], sz);                                     \
            xn = dot2(wi2[q], XV[q], xn);                                     \
        }                                                                     \
        if (PF) { load_x<InT, IN_DIM>(XV, x + xoff); xoff += xstep; }         \
        float hn = bhn;                                                       \
        _Pragma("unroll")                                                     \
        for (int j = 0; j < Hh; ++j) {                                        \
            sr = fmaf(wh0[j], h[j], sr);                                      \
            sz = fmaf(wh1[j], h[j], sz);                                      \
            hn = fmaf(wh2[j], h[j], hn);                                      \
        }                                                                     \
        float r  = __builtin_amdgcn_rcpf(1.f + __builtin_amdgcn_exp2f(sr));   \
        float z  = __builtin_amdgcn_rcpf(1.f + __builtin_amdgcn_exp2f(sz));   \
        float vS = fminf(fmaf(r, hn, xn), 60.f);  /* NaN guard, v -> -inf */  \
        float e2 = __builtin_amdgcn_exp2f(vS);                                \
        float nn = (1.f - e2) * __builtin_amdgcn_rcpf(1.f + e2);              \
        float hnew = fmaf(z, hown - nn, nn);      /* (1-z)*n + z*h */         \
        hown = hnew;                                                          \
        if (!LAST) { out[ooff] = (f16)hnew; ooff += ostep; }                  \
        hsh[hbase + lane8] = hnew;                                            \
        __builtin_amdgcn_wave_barrier();                                      \
        const float4* hp = (const float4*)&hsh[hbase];                        \
        float4 hA = hp[0], hB = hp[1];                                        \
        h[0] = hA.x; h[1] = hA.y; h[2] = hA.z; h[3] = hA.w;                   \
        h[4] = hB.x; h[5] = hB.y; h[6] = hB.z; h[7] = hB.w;                   \
    }

    int s = 0;
    for (; s + 2 < steps; s += 2) {
        GRU_STEP(xa, true);
        GRU_STEP(xb, true);
    }
    GRU_STEP(xa, false);
    if (steps > 1) GRU_STEP(xb, false);
#undef GRU_STEP

    if (LAST) last[(size_t)seq * 16 + dir * 8 + lane8] = hown;
}

// last (n,16) fp32 -> lin1(16->8) -> LeakyReLU(0.2) -> lin2(8->8) -> fp32 out
__global__ void head_kernel(const float* __restrict__ last,
                            const float* __restrict__ w1, const float* __restrict__ b1,
                            const float* __restrict__ w2, const float* __restrict__ b2,
                            float* __restrict__ out, int n)
{
    int i = blockIdx.x * blockDim.x + threadIdx.x;
    if (i >= n) return;
    const float* v = last + (size_t)i * 16;
    float h1[8];
#pragma unroll
    for (int j = 0; j < 8; ++j) {
        float a = b1[j];
#pragma unroll
        for (int k = 0; k < 16; ++k) a = fmaf(w1[j * 16 + k], v[k], a);
        h1[j] = a >= 0.f ? a : 0.2f * a;
    }
#pragma unroll
    for (int j = 0; j < 8; ++j) {
        float o = b2[j];
#pragma unroll
        for (int k = 0; k < 8; ++k) o = fmaf(w2[j * 8 + k], h1[k], o);
        out[(size_t)i * 8 + j] = o;
    }
}

extern "C" void kernel_launch(void* const* d_in, const int* in_sizes, int n_in,
                              void* d_out, int out_size, void* d_ws, size_t ws_size,
                              hipStream_t stream)
{
    const float* raw  = (const float*)d_in[0];
    const float* Wih0 = (const float*)d_in[1];
    const float* Whh0 = (const float*)d_in[2];
    const float* bih0 = (const float*)d_in[3];
    const float* bhh0 = (const float*)d_in[4];
    const float* WihR = (const float*)d_in[5];
    const float* WhhR = (const float*)d_in[6];
    const float* bihR = (const float*)d_in[7];
    const float* bhhR = (const float*)d_in[8];
    const float* w1   = (const float*)d_in[9];
    const float* b1   = (const float*)d_in[10];
    const float* w2   = (const float*)d_in[11];
    const float* b2   = (const float*)d_in[12];

    const int n = in_sizes[0] / (TT * Hh);        // 12800 sequences
    const size_t bufE = (size_t)n * TT * 16;      // elements per (n,T,16) buffer
    dim3 blk(64);
    dim3 grid((unsigned)((2 * n) / 8));           // 8 units per 64-thread block
    dim3 hblk(256);
    dim3 hgrid((unsigned)((n + 255) / 256));

    // f16 inter-layer buffers (same footprint as the previous bf16 path,
    // 8x finer quantization), feed v_dot2_f32_f16 directly.
    f16* bufA   = (f16*)d_ws;
    f16* bufB   = bufA + bufE;
    float* lastb = (float*)(bufB + bufE);

    gru_scan<float, 8, false><<<grid, blk, 0, stream>>>(
        raw, Wih0, Whh0, bih0, bhh0, bufA, (float*)nullptr, n);
    gru_scan<f16, 16, false><<<grid, blk, 0, stream>>>(
        bufA, WihR + 0 * 2 * G3 * 16, WhhR + 0 * 2 * G3 * 8,
        bihR + 0 * 2 * G3, bhhR + 0 * 2 * G3, bufB, (float*)nullptr, n);
    gru_scan<f16, 16, false><<<grid, blk, 0, stream>>>(
        bufB, WihR + 1 * 2 * G3 * 16, WhhR + 1 * 2 * G3 * 8,
        bihR + 1 * 2 * G3, bhhR + 1 * 2 * G3, bufA, (float*)nullptr, n);
    gru_scan<f16, 16, true><<<grid, blk, 0, stream>>>(
        bufA, WihR + 2 * 2 * G3 * 16, WhhR + 2 * 2 * G3 * 8,
        bihR + 2 * 2 * G3, bhhR + 2 * 2 * G3, (f16*)nullptr, lastb, n);
    head_kernel<<<hgrid, hblk, 0, stream>>>(
        lastb, w1, b1, w2, b2, (float*)d_out, n);
}

// Round 3
// 1419.383 us; speedup vs baseline: 1.3110x; 1.0536x over previous
//
#include <hip/hip_runtime.h>
#include <type_traits>

#define DEVINL __device__ __forceinline__

typedef __fp16 f16;
typedef __fp16 f16x2 __attribute__((ext_vector_type(2)));
typedef __fp16 f16x8 __attribute__((ext_vector_type(8)));

constexpr int Hh = 8;    // hidden size
constexpr int G3 = 24;   // 3*H gate rows
constexpr int TT = 512;  // timesteps

// Activation scales folded into weights/biases at register-load time:
//   sigmoid(v) = rcp(1 + exp2(-log2e * v))
//   tanh(v)    = (1 - e2) * rcp(1 + e2),  e2 = exp2(-2*log2e * v)
constexpr float SNEG  = -1.44269504088896340736f;  // -log2(e)
constexpr float SNEG2 = -2.88539008177792681472f;  // -2*log2(e)

DEVINL float dot2(f16x2 a, f16x2 b, float c) {
#if __has_builtin(__builtin_amdgcn_fdot2)
    return __builtin_amdgcn_fdot2(a, b, c, false);   // v_dot2_f32_f16: 2 MAC/instr
#else
    return fmaf((float)a[1], (float)b[1], fmaf((float)a[0], (float)b[0], c));
#endif
}

template <typename InT, int IN_DIM>
DEVINL void load_x(f16x2* d, const InT* p) {
    if constexpr (std::is_same<InT, float>::value) {
        const float4* p4 = (const float4*)p;
#pragma unroll
        for (int q = 0; q < IN_DIM / 4; ++q) {
            float4 v = p4[q];
            d[2 * q]     = __builtin_amdgcn_cvt_pkrtz(v.x, v.y);
            d[2 * q + 1] = __builtin_amdgcn_cvt_pkrtz(v.z, v.w);
        }
    } else {
        const f16x8* p8 = (const f16x8*)p;
#pragma unroll
        for (int c = 0; c < IN_DIM / 8; ++c) {
            f16x8 v = p8[c];
            d[4 * c + 0] = __builtin_shufflevector(v, v, 0, 1);
            d[4 * c + 1] = __builtin_shufflevector(v, v, 2, 3);
            d[4 * c + 2] = __builtin_shufflevector(v, v, 4, 5);
            d[4 * c + 3] = __builtin_shufflevector(v, v, 6, 7);
        }
    }
}

// One (sequence, direction) unit per 8 lanes. Lane i owns gate rows {i, 8+i,
// 16+i}. Input AND recurrent projections in f16 v_dot2 (2 MAC/instr); the
// own-lane h chain (z*h term) stays fp32. h all-gather in f16: 1 ds_write_b16
// + 1 ds_read_b128 per step (wave-synchronous, conflict-free).
// Prefetch depth 2 with manual ping-pong (no register copies).
template <typename InT, int IN_DIM, bool LAST>
__global__ __launch_bounds__(64, 2) void gru_scan(
    const InT* __restrict__ x,           // (n, T, IN_DIM)
    const float* __restrict__ Wih,       // (2, 24, IN_DIM)
    const float* __restrict__ Whh,       // (2, 24, 8)
    const float* __restrict__ bih,       // (2, 24)
    const float* __restrict__ bhh,       // (2, 24)
    f16* __restrict__ out,               // (n, T, 16): fwd->[0:8], bwd->[8:16]
    float* __restrict__ last,            // (n, 16) only when LAST
    int n)
{
    const int tid   = threadIdx.x;
    const int lane8 = tid & 7;
    const int unit  = blockIdx.x * 8 + (tid >> 3);
    const int dir   = unit >= n ? 1 : 0;       // blocks dir-uniform (n % 8 == 0)
    const int seq   = unit - dir * n;

    const int g0 = lane8, g1 = 8 + lane8, g2 = 16 + lane8;

    __shared__ __align__(16) f16 hsh[64];      // 8 units x 8 f16 h-values
    const int hbase = (tid >> 3) * 8;

    // ---- weights into registers, activation scale pre-folded ----
    const float* Wd = Wih + (size_t)dir * G3 * IN_DIM;
    f16x2 wi0[IN_DIM / 2], wi1[IN_DIM / 2], wi2[IN_DIM / 2];
#pragma unroll
    for (int q = 0; q < IN_DIM / 2; ++q) {
        wi0[q] = __builtin_amdgcn_cvt_pkrtz(Wd[g0 * IN_DIM + 2 * q] * SNEG,
                                            Wd[g0 * IN_DIM + 2 * q + 1] * SNEG);
        wi1[q] = __builtin_amdgcn_cvt_pkrtz(Wd[g1 * IN_DIM + 2 * q] * SNEG,
                                            Wd[g1 * IN_DIM + 2 * q + 1] * SNEG);
        wi2[q] = __builtin_amdgcn_cvt_pkrtz(Wd[g2 * IN_DIM + 2 * q] * SNEG2,
                                            Wd[g2 * IN_DIM + 2 * q + 1] * SNEG2);
    }
    const float* Hd = Whh + (size_t)dir * G3 * Hh;
    f16x2 wh0[Hh / 2], wh1[Hh / 2], wh2[Hh / 2];
#pragma unroll
    for (int q = 0; q < Hh / 2; ++q) {
        wh0[q] = __builtin_amdgcn_cvt_pkrtz(Hd[g0 * Hh + 2 * q] * SNEG,
                                            Hd[g0 * Hh + 2 * q + 1] * SNEG);
        wh1[q] = __builtin_amdgcn_cvt_pkrtz(Hd[g1 * Hh + 2 * q] * SNEG,
                                            Hd[g1 * Hh + 2 * q + 1] * SNEG);
        wh2[q] = __builtin_amdgcn_cvt_pkrtz(Hd[g2 * Hh + 2 * q] * SNEG2,
                                            Hd[g2 * Hh + 2 * q + 1] * SNEG2);
    }
    const float br  = (bih[dir * G3 + g0] + bhh[dir * G3 + g0]) * SNEG;
    const float bz  = (bih[dir * G3 + g1] + bhh[dir * G3 + g1]) * SNEG;
    const float bxn = bih[dir * G3 + g2] * SNEG2;
    const float bhn = bhh[dir * G3 + g2] * SNEG2;

    f16x2 h2[Hh / 2];
#pragma unroll
    for (int q = 0; q < Hh / 2; ++q) h2[q] = f16x2{(f16)0.f, (f16)0.f};
    float hown = 0.f;                          // this lane's own h element (fp32)

    const int t0 = dir ? (TT - 1) : 0;
    const int xstep = dir ? -IN_DIM : IN_DIM;
    const int ostep = dir ? -16 : 16;
    const InT* xp = x + (size_t)(seq * TT + t0) * IN_DIM;
    f16* op = LAST ? nullptr
                   : out + (size_t)(seq * TT + t0) * 16 + dir * 8 + lane8;

    // layer-3 backward: only out_b[:, T-1] is consumed = its FIRST step
    const int steps = (LAST && dir) ? 1 : TT;

    f16x2 xa[IN_DIM / 2], xb[IN_DIM / 2];
    load_x<InT, IN_DIM>(xa, xp); xp += xstep;
    if (steps > 1) { load_x<InT, IN_DIM>(xb, xp); xp += xstep; }

#define GRU_STEP(XV, PF)                                                      \
    {                                                                         \
        float sr = br, sz = bz, xn = bxn;                                     \
        _Pragma("unroll")                                                     \
        for (int q = 0; q < IN_DIM / 2; ++q) {                                \
            sr = dot2(wi0[q], XV[q], sr);                                     \
            sz = dot2(wi1[q], XV[q], sz);                                     \
            xn = dot2(wi2[q], XV[q], xn);                                     \
        }                                                                     \
        if (PF) { load_x<InT, IN_DIM>(XV, xp); xp += xstep; }                 \
        float hn = bhn;                                                       \
        _Pragma("unroll")                                                     \
        for (int q = 0; q < Hh / 2; ++q) {                                    \
            sr = dot2(wh0[q], h2[q], sr);                                     \
            sz = dot2(wh1[q], h2[q], sz);                                     \
            hn = dot2(wh2[q], h2[q], hn);                                     \
        }                                                                     \
        float r  = __builtin_amdgcn_rcpf(1.f + __builtin_amdgcn_exp2f(sr));   \
        float z  = __builtin_amdgcn_rcpf(1.f + __builtin_amdgcn_exp2f(sz));   \
        float vS = fminf(fmaf(r, hn, xn), 60.f);  /* NaN guard, v -> -inf */  \
        float e2 = __builtin_amdgcn_exp2f(vS);                                \
        float nn = (1.f - e2) * __builtin_amdgcn_rcpf(1.f + e2);              \
        float hnew = fmaf(z, hown - nn, nn);      /* (1-z)*n + z*h */         \
        hown = hnew;                                                          \
        f16 hf = (f16)hnew;                       /* one cvt: out + LDS */    \
        if (!LAST) { *op = hf; op += ostep; }                                 \
        hsh[hbase + lane8] = hf;                                              \
        __builtin_amdgcn_wave_barrier();                                      \
        f16x8 hv = *(const f16x8*)&hsh[hbase];                                \
        h2[0] = __builtin_shufflevector(hv, hv, 0, 1);                        \
        h2[1] = __builtin_shufflevector(hv, hv, 2, 3);                        \
        h2[2] = __builtin_shufflevector(hv, hv, 4, 5);                        \
        h2[3] = __builtin_shufflevector(hv, hv, 6, 7);                        \
    }

    int s = 0;
    for (; s + 2 < steps; s += 2) {
        GRU_STEP(xa, true);
        GRU_STEP(xb, true);
    }
    GRU_STEP(xa, false);
    if (steps > 1) GRU_STEP(xb, false);
#undef GRU_STEP

    if (LAST) last[(size_t)seq * 16 + dir * 8 + lane8] = hown;
}

// last (n,16) fp32 -> lin1(16->8) -> LeakyReLU(0.2) -> lin2(8->8) -> fp32 out
__global__ void head_kernel(const float* __restrict__ last,
                            const float* __restrict__ w1, const float* __restrict__ b1,
                            const float* __restrict__ w2, const float* __restrict__ b2,
                            float* __restrict__ out, int n)
{
    int i = blockIdx.x * blockDim.x + threadIdx.x;
    if (i >= n) return;
    const float* v = last + (size_t)i * 16;
    float h1[8];
#pragma unroll
    for (int j = 0; j < 8; ++j) {
        float a = b1[j];
#pragma unroll
        for (int k = 0; k < 16; ++k) a = fmaf(w1[j * 16 + k], v[k], a);
        h1[j] = a >= 0.f ? a : 0.2f * a;
    }
#pragma unroll
    for (int j = 0; j < 8; ++j) {
        float o = b2[j];
#pragma unroll
        for (int k = 0; k < 8; ++k) o = fmaf(w2[j * 8 + k], h1[k], o);
        out[(size_t)i * 8 + j] = o;
    }
}

extern "C" void kernel_launch(void* const* d_in, const int* in_sizes, int n_in,
                              void* d_out, int out_size, void* d_ws, size_t ws_size,
                              hipStream_t stream)
{
    const float* raw  = (const float*)d_in[0];
    const float* Wih0 = (const float*)d_in[1];
    const float* Whh0 = (const float*)d_in[2];
    const float* bih0 = (const float*)d_in[3];
    const float* bhh0 = (const float*)d_in[4];
    const float* WihR = (const float*)d_in[5];
    const float* WhhR = (const float*)d_in[6];
    const float* bihR = (const float*)d_in[7];
    const float* bhhR = (const float*)d_in[8];
    const float* w1   = (const float*)d_in[9];
    const float* b1   = (const float*)d_in[10];
    const float* w2   = (const float*)d_in[11];
    const float* b2   = (const float*)d_in[12];

    const int n = in_sizes[0] / (TT * Hh);        // 12800 sequences
    const size_t bufE = (size_t)n * TT * 16;      // elements per (n,T,16) buffer
    dim3 blk(64);
    dim3 grid((unsigned)((2 * n) / 8));           // 8 units per 64-thread block
    dim3 hblk(256);
    dim3 hgrid((unsigned)((n + 255) / 256));

    // f16 inter-layer buffers feed v_dot2_f32_f16 directly.
    f16* bufA   = (f16*)d_ws;
    f16* bufB   = bufA + bufE;
    float* lastb = (float*)(bufB + bufE);

    gru_scan<float, 8, false><<<grid, blk, 0, stream>>>(
        raw, Wih0, Whh0, bih0, bhh0, bufA, (float*)nullptr, n);
    gru_scan<f16, 16, false><<<grid, blk, 0, stream>>>(
        bufA, WihR + 0 * 2 * G3 * 16, WhhR + 0 * 2 * G3 * 8,
        bihR + 0 * 2 * G3, bhhR + 0 * 2 * G3, bufB, (float*)nullptr, n);
    gru_scan<f16, 16, false><<<grid, blk, 0, stream>>>(
        bufB, WihR + 1 * 2 * G3 * 16, WhhR + 1 * 2 * G3 * 8,
        bihR + 1 * 2 * G3, bhhR + 1 * 2 * G3, bufA, (float*)nullptr, n);
    gru_scan<f16, 16, true><<<grid, blk, 0, stream>>>(
        bufA, WihR + 2 * 2 * G3 * 16, WhhR + 2 * 2 * G3 * 8,
        bihR + 2 * 2 * G3, bhhR + 2 * 2 * G3, (f16*)nullptr, lastb, n);
    head_kernel<<<hgrid, hblk, 0, stream>>>(
        lastb, w1, b1, w2, b2, (float*)d_out, n);
}